// Round 5
// baseline (980.711 us; speedup 1.0000x reference)
//
#include <hip/hip_runtime.h>

typedef __bf16 bf16x8 __attribute__((ext_vector_type(8)));
typedef __bf16 bf16x4 __attribute__((ext_vector_type(4)));
typedef float  f32x4  __attribute__((ext_vector_type(4)));

#define NB 8
#define NC 64
#define NH 256
#define NW 256
#define NT 16     // W tiles (jobs per batch)
#define WT 16     // core width per job
#define SEG 32    // steps between neighbor syncs == halo width per side
#define NS 5      // window subtiles: (WT + 2*SEG)/16
#define LDSW 82   // window + conv pad columns, w = wc0-1 .. wc0+80
#define LDSC 72   // ci stride: 144 B rows keep ds_read_b128 16B-aligned

// tanh(x) = 1 - 2/(1+e^{2x}); bounded, branch-free, NaN-free for finite x
__device__ __forceinline__ float fast_tanh(float x) {
    float e = __expf(2.0f * x);
    return 1.0f - 2.0f / (1.0f + e);
}

// 64 WGs x 512 threads: each WG runs TWO independent trapezoid jobs
// (batch b, tiles 2q and 2q+1). Waves 0-3 = job 0, waves 4-7 = job 1;
// each job is exactly the verified 4-wave SEG=32 kernel (1 wave/SIMD each).
// The jobs synchronize through PRIVATE LDS-atomic barriers (CDNA4 has no
// named HW barriers), so they drift in phase: each SIMD hosts one wave of
// each job at independent points in the step -> dependency stalls of one
// job are filled by issue work of the other (unlike lockstep s_barrier,
// which round 4 showed makes things worse). Adjacent-tile pairing also
// makes one of the two neighbor halo exchanges intra-CU.
__global__ __launch_bounds__(512, 1)
void spconv_trap(const float* __restrict__ Xg,
                 const float* __restrict__ Wg,
                 const float* __restrict__ Bg,
                 float* __restrict__ Yg,
                 int* __restrict__ flags)
{
    const int b    = blockIdx.x & 7;
    const int q    = blockIdx.x >> 3;   // 0..7: tile pair
    const int tid  = threadIdx.x;
    const int jl   = tid >> 8;          // job 0/1 (waves 0-3 / 4-7)
    const int jt   = tid & 255;         // thread id within job
    const int wv   = jt >> 6;           // 0..3: wave-in-job = co-tile
    const int lane = tid & 63;
    const int g    = lane >> 4;         // quad
    const int lm   = lane & 15;
    const int t    = 2 * q + jl;        // this job's W tile
    const int w0   = t * WT;
    const int wc0  = w0 - SEG;          // window start

    __shared__ __bf16 buf[2][2][LDSW][LDSC]; // [job][pp][w][ci], 46.1 KB
    __shared__ int jctr[2][32];              // per-job barrier counters (padded)

    if (tid < 2) jctr[tid][0] = 0;

    // ---- A fragments (this wave's co-tile), resident in VGPRs ----
    // chunk c: k-tap = c>>1, ci0 = 32*(c&1)+8g; A[m=lm][q=8g+j]=W[co][ci0+j][k]
    bf16x8 afrag[6];
    {
        const int co = wv * 16 + lm;
        #pragma unroll
        for (int c = 0; c < 6; ++c) {
            const int k = c >> 1, ci0 = 32 * (c & 1) + 8 * g;
            bf16x8 a;
            #pragma unroll
            for (int j = 0; j < 8; ++j)
                a[j] = (__bf16)Wg[(co * NC + ci0 + j) * 3 + k];
            afrag[c] = a;
        }
    }
    float bias_r[4];
    #pragma unroll
    for (int i = 0; i < 4; ++i)
        bias_r[i] = Bg[wv * 16 + 4 * g + i];

    // ---- init: BOTH buffers of THIS job <- X row 0 (clamped outside) ----
    {
        const int ci = jt & 63;
        for (int r = (jt >> 6); r < LDSW; r += 4) {
            const int w = wc0 - 1 + r;
            float v = (w >= 0 && w < NW)
                    ? Xg[((size_t)(b * NC + ci) * NH + 0) * NW + w] : 0.0f;
            const __bf16 bv = (__bf16)v;
            buf[jl][0][r][ci] = bv;
            buf[jl][1][r][ci] = bv;
        }
    }
    // Y row 0 = X row 0 (exact fp32 passthrough), core columns only
    #pragma unroll
    for (int i = 0; i < 4; ++i) {
        const int co = wv * 16 + 4 * g + i;
        const size_t idx = ((size_t)(b * NC + co) * NH + 0) * NW + w0 + lm;
        Yg[idx] = Xg[idx];
    }

    // per-lane window-column validity (fixed for the whole kernel)
    bool wok[NS];
    #pragma unroll
    for (int s = 0; s < NS; ++s) {
        const int w = wc0 + 16 * s + lm;
        wok[s] = (w >= 0 && w < NW);
    }

    // ping-pong X prefetch registers; preload row 1 into xA
    float xA[NS][4], xB[NS][4];
    #pragma unroll
    for (int s = 0; s < NS; ++s)
        #pragma unroll
        for (int i = 0; i < 4; ++i) {
            const int co = wv * 16 + 4 * g + i;
            const int w  = wc0 + 16 * s + lm;
            xA[s][i] = wok[s]
                ? Xg[((size_t)(b * NC + co) * NH + 1) * NW + w] : 0.0f;
        }
    __syncthreads();   // covers init of both jobs + jctr; never WG-wide again

    const int myflag = b * NT + t;

    // ---- per-job 4-wave barrier: monotonic LDS counter, lgkm-only drain ----
    // (does NOT wait vmcnt: X prefetch loads and Y store acks float across)
    int ph = 0;
    auto jbar = [&]() {
        ++ph;
        asm volatile("s_waitcnt lgkmcnt(0)" ::: "memory");
        __builtin_amdgcn_sched_barrier(0);
        if (lane == 0)
            __hip_atomic_fetch_add(&jctr[jl][0], 1,
                                   __ATOMIC_RELAXED, __HIP_MEMORY_SCOPE_WORKGROUP);
        while (__hip_atomic_load(&jctr[jl][0],
                                 __ATOMIC_RELAXED, __HIP_MEMORY_SCOPE_WORKGROUP)
               < 4 * ph) {}
        __builtin_amdgcn_sched_barrier(0);
    };

    // p is a compile-time constant at each call site (body inlined twice per
    // unrolled pair), so LDS buffer selection folds to immediates.
    auto body = [&](int h, int p, float (&xcur)[NS][4], float (&xnext)[NS][4]) {
        // ---- prefetch X[h+1] at step top: ~1 full step to cover HBM ----
        if (h + 1 < NH) {
            #pragma unroll
            for (int s = 0; s < NS; ++s)
                #pragma unroll
                for (int i = 0; i < 4; ++i) {
                    const int co = wv * 16 + 4 * g + i;
                    const int w  = wc0 + 16 * s + lm;
                    xnext[s][i] = wok[s]
                        ? Xg[((size_t)(b * NC + co) * NH + h + 1) * NW + w] : 0.0f;
                }
        }

        // ---- conv over NS w-subtiles from buf[jl][p]: D = sum_c A_c*B_c ----
        float yv[NS][4];
        #pragma unroll
        for (int s = 0; s < NS; ++s) {
            f32x4 acc = {0.f, 0.f, 0.f, 0.f};
            #pragma unroll
            for (int c = 0; c < 6; ++c) {
                const bf16x8 bfr = *(const bf16x8*)
                    &buf[jl][p][16 * s + lm + (c >> 1)][32 * (c & 1) + 8 * g];
                acc = __builtin_amdgcn_mfma_f32_16x16x32_bf16(afrag[c], bfr, acc, 0, 0, 0);
            }
            #pragma unroll
            for (int i = 0; i < 4; ++i)
                yv[s][i] = xcur[s][i] + fast_tanh(acc[i] + bias_r[i]);
        }
        // ---- store core columns (subtile SEG/16 = 2) to global, fp32 ----
        #pragma unroll
        for (int i = 0; i < 4; ++i) {
            const int co = wv * 16 + 4 * g + i;
            Yg[((size_t)(b * NC + co) * NH + h) * NW + w0 + lm] = yv[SEG / 16][i];
        }

        // ---- write new row into the OTHER buffer (no read-WAR barrier) ----
        #pragma unroll
        for (int s = 0; s < NS; ++s) {
            bf16x4 pk;
            #pragma unroll
            for (int i = 0; i < 4; ++i)
                pk[i] = wok[s] ? (__bf16)yv[s][i] : (__bf16)0.0f;
            *(bf16x4*)&buf[jl][p ^ 1][16 * s + lm + 1][wv * 16 + 4 * g] = pk;
        }

        const bool boundary = (h < NH - 1) && ((h & (SEG - 1)) == 0);
        if (boundary) {
            const int k = h >> 5;          // completed segment index, 1..7
            __threadfence();               // publish my Y stores (drains vmcnt)
            jbar();                        // all 4 waves' fences done
            if (jt == 0)
                __hip_atomic_store(&flags[myflag], k,
                                   __ATOMIC_RELEASE, __HIP_MEMORY_SCOPE_AGENT);
            // spin in two different waves so the waits overlap
            if (t > 0 && jt == 64) {
                while (__hip_atomic_load(&flags[myflag - 1], __ATOMIC_ACQUIRE,
                                         __HIP_MEMORY_SCOPE_AGENT) < k)
                    __builtin_amdgcn_s_sleep(2);
            }
            if (t < NT - 1 && jt == 192) {
                while (__hip_atomic_load(&flags[myflag + 1], __ATOMIC_ACQUIRE,
                                         __HIP_MEMORY_SCOPE_AGENT) < k)
                    __builtin_amdgcn_s_sleep(2);
            }
            jbar();
            // refill halo regions of buf[jl][p^1] from neighbors' Y[h], f32x4:
            // 2 sides x 64 ci x 8 w-quads = 1024 tasks, 4 per job thread
            for (int idx = jt; idx < 2 * NC * (SEG / 4); idx += 256) {
                const int q8   = idx & 7;
                const int ci   = (idx >> 3) & 63;
                const int side = idx >> 9;             // 0 = left, 1 = right
                const bool have = side ? (t < NT - 1) : (t > 0);
                if (have) {
                    const int wq = w0 - SEG + 4 * q8 + side * (WT + SEG);
                    const int r  = 4 * q8 + 1 + side * (WT + SEG);
                    const f32x4 v = *(const f32x4*)
                        &Yg[((size_t)(b * NC + ci) * NH + h) * NW + wq];
                    #pragma unroll
                    for (int i2 = 0; i2 < 4; ++i2)
                        buf[jl][p ^ 1][r + i2][ci] = (__bf16)v[i2];
                }
            }
            jbar();
        } else {
            jbar();   // per-job: new-row ds_writes visible, vmcnt NOT drained
        }
    };

    // h odd -> reads buf[jl][0], writes buf[jl][1]; h even -> the reverse.
    // Boundaries (h % 32 == 0) always land in the second body (p = 1).
    for (int h = 1; h < NH; h += 2) {
        body(h, 0, xA, xB);
        if (h + 1 < NH) body(h + 1, 1, xB, xA);
    }
}

extern "C" void kernel_launch(void* const* d_in, const int* in_sizes, int n_in,
                              void* d_out, int out_size, void* d_ws, size_t ws_size,
                              hipStream_t stream)
{
    const float* X  = (const float*)d_in[0];
    const float* Wc = (const float*)d_in[1];
    const float* Bc = (const float*)d_in[2];
    float* Y        = (float*)d_out;
    int* flags      = (int*)d_ws;   // 128 ints; d_ws is poisoned 0xAA -> memset

    hipMemsetAsync(d_ws, 0, NB * NT * sizeof(int), stream);

    dim3 grid(NB * NT / 2);   // 64 WGs x 8 waves (2 jobs): co-resident, spin-safe
    dim3 block(512);
    hipLaunchKernelGGL(spconv_trap, grid, block, 0, stream, X, Wc, Bc, Y, flags);
}